// Round 12
// baseline (8384.152 us; speedup 1.0000x reference)
//
#include <hip/hip_runtime.h>
#include <stdint.h>

#define B_    32
#define S_    1024
#define HIN   1024
#define NBLK  64
#define DBLK  16
#define HOUT  1024
#define NGATE 1152   // 64 i + 64 o + 1024 g
#define NSLICE 32    // gate slices (32 Ug rows + 2 Ui + 2 Uo each)

typedef __attribute__((ext_vector_type(8))) __bf16 bf16x8;
typedef __attribute__((ext_vector_type(4))) float  f32x4;

__device__ __forceinline__ unsigned short f2bf(float f) {
    union { float f; unsigned u; } v; v.f = f;
    return (unsigned short)((v.u + 0x7fffu + ((v.u >> 16) & 1u)) >> 16);
}
__device__ __forceinline__ float bf2f(unsigned short h) {
    union { unsigned u; float f; } v; v.u = ((unsigned)h) << 16; return v.f;
}
// fp32 -> hi+lo bf16 (v ~= hi + lo, residual <= 2^-18 |v|)
__device__ __forceinline__ void split1(float f, unsigned short& hi, unsigned short& lo) {
    hi = f2bf(f);
    lo = f2bf(f - bf2f(hi));
}

// gate-row mapping for a slice: rows 0..31 = Ug[slice*32+r], 32..33 = Ui[2s..], 34..35 = Uo[2s..]
__device__ __forceinline__ int slice_row(int slice, int r) {
    return (r < 32) ? (128 + slice * 32 + r)
         : (r < 34) ? (slice * 2 + (r - 32))
                    : (64 + slice * 2 + (r - 34));
}

// ---------------- phase 0: split W,U into hi/lo bf16; split h0 into planes ----------------
__global__ void k_init(const float* __restrict__ Wi, const float* __restrict__ Wo,
                       const float* __restrict__ Wg,
                       const float* __restrict__ Ui, const float* __restrict__ Uo,
                       const float* __restrict__ Ug, const float* __restrict__ h0,
                       unsigned short* __restrict__ WsH, unsigned short* __restrict__ WsL,
                       unsigned short* __restrict__ UsH, unsigned short* __restrict__ UsL,
                       unsigned short* __restrict__ hbH, unsigned short* __restrict__ hbL)
{
    int idx = blockIdx.x * 256 + threadIdx.x;
    const int nW = NGATE * HOUT / 4;           // 294912 quads per matrix set
    float4 v; unsigned short *dH, *dL;
    if (idx < nW) {
        int f = idx * 4; int row = f >> 10, k = f & 1023;
        const float* src = (row < 64)  ? (Wi + (size_t)row * HIN)
                         : (row < 128) ? (Wo + (size_t)(row - 64) * HIN)
                                       : (Wg + (size_t)(row - 128) * HIN);
        v = *(const float4*)(src + k);
        dH = WsH + f; dL = WsL + f;
    } else if (idx < 2 * nW) {
        int f = (idx - nW) * 4; int row = f >> 10, k = f & 1023;
        const float* src = (row < 64)  ? (Ui + (size_t)row * HOUT)
                         : (row < 128) ? (Uo + (size_t)(row - 64) * HOUT)
                                       : (Ug + (size_t)(row - 128) * HOUT);
        v = *(const float4*)(src + k);
        dH = UsH + f; dL = UsL + f;
    } else {
        int f = (idx - 2 * nW) * 4;
        if (f >= B_ * HOUT) return;
        v = *(const float4*)(h0 + f);
        dH = hbH + f; dL = hbL + f;            // slot 0
    }
    unsigned short th[4], tl[4];
    split1(v.x, th[0], tl[0]); split1(v.y, th[1], tl[1]);
    split1(v.z, th[2], tl[2]); split1(v.w, th[3], tl[3]);
    *(uint2*)dH = *(const uint2*)th;
    *(uint2*)dL = *(const uint2*)tl;
}

// ---------------- phase 1: gate pre-projection GEMM (bf16x3) ----------------
#define BM 128
#define BN 128
#define BK 32
#define LDP 56

__global__ __launch_bounds__(256) void k_gates(
    const float* __restrict__ x,
    const unsigned short* __restrict__ WsH, const unsigned short* __restrict__ WsL,
    const float* __restrict__ bi, const float* __restrict__ bo, const float* __restrict__ bg,
    float* __restrict__ c_out, float* __restrict__ h_out)
{
    __shared__ unsigned short AlH[BM][LDP], AlL[BM][LDP];
    __shared__ unsigned short BlH[BN][LDP], BlL[BN][LDP];
    const int tid  = threadIdx.x;
    const int bm   = blockIdx.x, bn = blockIdx.y;
    const int wave = tid >> 6,  lane = tid & 63;
    const int l15  = lane & 15, l4 = lane >> 4;
    const int wm   = wave >> 1, wn = wave & 1;
    const int rbase = tid >> 3;          // 0..31
    const int c4    = (tid & 7) * 4;     // 0..28

    f32x4 acc[4][4] = {};

    for (int kk = 0; kk < HIN; kk += BK) {
        #pragma unroll
        for (int i = 0; i < 4; ++i) {
            int row = rbase + 32 * i;
            float4 v = *(const float4*)(x + (size_t)(bm * BM + row) * HIN + kk + c4);
            unsigned short th[4], tl[4];
            split1(v.x, th[0], tl[0]); split1(v.y, th[1], tl[1]);
            split1(v.z, th[2], tl[2]); split1(v.w, th[3], tl[3]);
            *(uint2*)&AlH[row][c4] = *(const uint2*)th;
            *(uint2*)&AlL[row][c4] = *(const uint2*)tl;
            int n = bn * BN + row;
            *(uint2*)&BlH[row][c4] = *(const uint2*)(WsH + (size_t)n * HIN + kk + c4);
            *(uint2*)&BlL[row][c4] = *(const uint2*)(WsL + (size_t)n * HIN + kk + c4);
        }
        __syncthreads();
        uint4 ah[4], al[4], bh4[4], bl4[4];
        #pragma unroll
        for (int mi = 0; mi < 4; ++mi) {
            ah[mi] = *(const uint4*)&AlH[wm * 64 + mi * 16 + l15][l4 * 8];
            al[mi] = *(const uint4*)&AlL[wm * 64 + mi * 16 + l15][l4 * 8];
        }
        #pragma unroll
        for (int ni = 0; ni < 4; ++ni) {
            bh4[ni] = *(const uint4*)&BlH[wn * 64 + ni * 16 + l15][l4 * 8];
            bl4[ni] = *(const uint4*)&BlL[wn * 64 + ni * 16 + l15][l4 * 8];
        }
        #pragma unroll
        for (int mi = 0; mi < 4; ++mi) {
            #pragma unroll
            for (int ni = 0; ni < 4; ++ni) {
                acc[mi][ni] = __builtin_amdgcn_mfma_f32_16x16x32_bf16(
                    __builtin_bit_cast(bf16x8, ah[mi]), __builtin_bit_cast(bf16x8, bh4[ni]),
                    acc[mi][ni], 0, 0, 0);
                acc[mi][ni] = __builtin_amdgcn_mfma_f32_16x16x32_bf16(
                    __builtin_bit_cast(bf16x8, ah[mi]), __builtin_bit_cast(bf16x8, bl4[ni]),
                    acc[mi][ni], 0, 0, 0);
                acc[mi][ni] = __builtin_amdgcn_mfma_f32_16x16x32_bf16(
                    __builtin_bit_cast(bf16x8, al[mi]), __builtin_bit_cast(bf16x8, bh4[ni]),
                    acc[mi][ni], 0, 0, 0);
            }
        }
        __syncthreads();
    }

    #pragma unroll
    for (int ni = 0; ni < 4; ++ni) {
        int n = bn * BN + wn * 64 + ni * 16 + l15;
        float bv = (n < 64) ? bi[n] : (n < 128) ? bo[n - 64] : bg[n - 128];
        #pragma unroll
        for (int mi = 0; mi < 4; ++mi) {
            #pragma unroll
            for (int r = 0; r < 4; ++r) {
                int m = bm * BM + wm * 64 + mi * 16 + l4 * 4 + r;
                float val = acc[mi][ni][r] + bv;
                if (n >= 128) {
                    h_out[(size_t)m * HOUT + (n - 128)] = val;
                } else if (n < 64) {
                    c_out[((size_t)m * NBLK + n) * DBLK + 0] = val;
                } else {
                    c_out[((size_t)m * NBLK + (n - 64)) * DBLK + 1] = val;
                }
            }
        }
    }
}

// ---------------- phase 2: persistent lockstep recurrence (bf16x3) ----------------
// 64 WGs x 256 thr. slice = bid&31, group = bid>>5 (batches [16g,+16)).
// R12 change vs R11 (5.08ms): 4-way K-SPLIT. Each wave owns K-quarter
// [256w,+256) = producer slices [8w,8w+8): it polls ONLY those 8 flags, stages
// ONLY its quarter (R11 asm bulk loads, same tid mapping), computes all 36 gate
// rows for its quarter, and combines via ds_add into double-buffered pre.
// A-plane is read from LDS ONCE (was 3x), no intra-step barrier until the
// combine: LDS traffic 460KB -> ~210KB/step, barriers 4 -> 2.
__global__ __launch_bounds__(256, 1) void k_rec(
    const float* __restrict__ c0,
    float* __restrict__ c_out, float* __restrict__ h_out,
    const unsigned short* __restrict__ UsH, const unsigned short* __restrict__ UsL,
    unsigned short* __restrict__ hbH, unsigned short* __restrict__ hbL,
    unsigned int* __restrict__ flags)
{
    __shared__ unsigned short Wlo[37][1032];   // 74.6 KB (row 36 = zeros)
    __shared__ unsigned short HaH[16][1032];   // 33 KB
    __shared__ unsigned short HaL[16][1032];   // 33 KB
    __shared__ float pre[2][16][52];           // 6.5 KB double-buffered combine

    const int tid   = threadIdx.x;
    const int slice = blockIdx.x & 31;
    const int group = blockIdx.x >> 5;     // 0 or 1
    const int wave  = tid >> 6, lane = tid & 63;
    const int l15   = lane & 15, l4 = lane >> 4;

    // fill Wlo (lo-plane weights) into LDS; row 36 zeroed
    for (int idx = tid; idx < 37 * 128; idx += 256) {
        int row = idx >> 7, c8 = idx & 127;
        uint4 v = make_uint4(0, 0, 0, 0);
        if (row < 36)
            v = *(const uint4*)(UsL + (size_t)slice_row(slice, row) * HOUT + c8 * 8);
        *(uint4*)&Wlo[row][c8 * 8] = v;
    }
    for (int i = tid; i < 2 * 16 * 52; i += 256)
        (&pre[0][0][0])[i] = 0.f;

    // hi-plane B-fragments for this wave's K-quarter: 3 nt-groups x 8 ks
    // (compiler may stream these from L2 each step; R11 showed that's fine)
    int wrow[3];
    uint4 bwh[3][8];
    #pragma unroll
    for (int nt = 0; nt < 3; ++nt) {
        int grow = nt * 16 + l15;
        bool valid = grow < 36;
        wrow[nt] = valid ? grow : 36;
        int srow = valid ? slice_row(slice, grow) : 0;
        const unsigned short* ph = UsH + (size_t)srow * HOUT + wave * 256 + l4 * 8;
        #pragma unroll
        for (int ks = 0; ks < 8; ++ks)
            bwh[nt][ks] = valid ? *(const uint4*)(ph + ks * 32) : make_uint4(0, 0, 0, 0);
    }

    // per-thread epilogue mapping: 2 consecutive h-cols
    const int e0   = tid * 2;
    const int bl   = e0 >> 5;             // 0..15 batch-in-group
    const int col0 = e0 & 31;             // even
    const int Bg   = group * 16 + bl;
    const int hcol = slice * 32 + col0;
    const int blkI = hcol >> 4, d0 = hcol & 15;
    float cr0 = c0[((size_t)Bg * NBLK + blkI) * DBLK + d0];
    float cr1 = c0[((size_t)Bg * NBLK + blkI) * DBLK + d0 + 1];

    unsigned int* flagbase = flags + (size_t)group * NSLICE * 32;
    unsigned int* myflag   = flagbase + slice * 32;                    // 128B apart
    unsigned int* pollfl   = flagbase + (wave * 8 + (lane & 7)) * 32;  // my 8 producers

    // step-0 gate preactivation prefetch
    size_t rowoff = (size_t)Bg * S_;
    float xg0 = h_out[rowoff * HOUT + hcol];
    float xg1 = h_out[rowoff * HOUT + hcol + 1];
    float xi  = c_out[(rowoff * NBLK + blkI) * DBLK + 0];
    float xo  = c_out[(rowoff * NBLK + blkI) * DBLK + 1];

    __syncthreads();   // Wlo + pre ready

    for (int t = 0; t < S_; ++t) {
        // ---- 1. per-wave poll: wait only for MY K-quarter's 8 producer slices
        if (t > 0) {
            unsigned v;
            do {
                v = __hip_atomic_load(pollfl, __ATOMIC_RELAXED, __HIP_MEMORY_SCOPE_AGENT);
            } while (!__all((int)(v >= (unsigned)t)));
            asm volatile("" ::: "memory");
        }

        // ---- 2. per-wave bulk-stage of MY quarter (R11 asm pattern; thread tid
        //         = wave*64+lane covers col-chunk tid*8B of all 16 rows)
        {
            const char* bH = (const char*)(hbH + ((size_t)(t & 1) * B_ + group * 16) * HOUT) + tid * 8;
            const char* bL = (const char*)(hbL + ((size_t)(t & 1) * B_ + group * 16) * HOUT) + tid * 8;
            unsigned long long vh[16], vl[16];
            asm volatile(
                "global_load_dwordx2 %0, %16, off sc0 sc1\n\t"
                "global_load_dwordx2 %1, %16, off offset:2048 sc0 sc1\n\t"
                "global_load_dwordx2 %2, %17, off sc0 sc1\n\t"
                "global_load_dwordx2 %3, %17, off offset:2048 sc0 sc1\n\t"
                "global_load_dwordx2 %4, %18, off sc0 sc1\n\t"
                "global_load_dwordx2 %5, %18, off offset:2048 sc0 sc1\n\t"
                "global_load_dwordx2 %6, %19, off sc0 sc1\n\t"
                "global_load_dwordx2 %7, %19, off offset:2048 sc0 sc1\n\t"
                "global_load_dwordx2 %8, %20, off sc0 sc1\n\t"
                "global_load_dwordx2 %9, %20, off offset:2048 sc0 sc1\n\t"
                "global_load_dwordx2 %10, %21, off sc0 sc1\n\t"
                "global_load_dwordx2 %11, %21, off offset:2048 sc0 sc1\n\t"
                "global_load_dwordx2 %12, %22, off sc0 sc1\n\t"
                "global_load_dwordx2 %13, %22, off offset:2048 sc0 sc1\n\t"
                "global_load_dwordx2 %14, %23, off sc0 sc1\n\t"
                "global_load_dwordx2 %15, %23, off offset:2048 sc0 sc1\n\t"
                : "=&v"(vh[0]), "=&v"(vh[1]), "=&v"(vh[2]), "=&v"(vh[3]),
                  "=&v"(vh[4]), "=&v"(vh[5]), "=&v"(vh[6]), "=&v"(vh[7]),
                  "=&v"(vh[8]), "=&v"(vh[9]), "=&v"(vh[10]), "=&v"(vh[11]),
                  "=&v"(vh[12]), "=&v"(vh[13]), "=&v"(vh[14]), "=&v"(vh[15])
                : "v"(bH), "v"(bH + 4096), "v"(bH + 8192), "v"(bH + 12288),
                  "v"(bH + 16384), "v"(bH + 20480), "v"(bH + 24576), "v"(bH + 28672)
                : "memory");
            asm volatile(
                "global_load_dwordx2 %0, %16, off sc0 sc1\n\t"
                "global_load_dwordx2 %1, %16, off offset:2048 sc0 sc1\n\t"
                "global_load_dwordx2 %2, %17, off sc0 sc1\n\t"
                "global_load_dwordx2 %3, %17, off offset:2048 sc0 sc1\n\t"
                "global_load_dwordx2 %4, %18, off sc0 sc1\n\t"
                "global_load_dwordx2 %5, %18, off offset:2048 sc0 sc1\n\t"
                "global_load_dwordx2 %6, %19, off sc0 sc1\n\t"
                "global_load_dwordx2 %7, %19, off offset:2048 sc0 sc1\n\t"
                "global_load_dwordx2 %8, %20, off sc0 sc1\n\t"
                "global_load_dwordx2 %9, %20, off offset:2048 sc0 sc1\n\t"
                "global_load_dwordx2 %10, %21, off sc0 sc1\n\t"
                "global_load_dwordx2 %11, %21, off offset:2048 sc0 sc1\n\t"
                "global_load_dwordx2 %12, %22, off sc0 sc1\n\t"
                "global_load_dwordx2 %13, %22, off offset:2048 sc0 sc1\n\t"
                "global_load_dwordx2 %14, %23, off sc0 sc1\n\t"
                "global_load_dwordx2 %15, %23, off offset:2048 sc0 sc1\n\t"
                "s_waitcnt vmcnt(0)\n\t"
                : "=&v"(vl[0]), "=&v"(vl[1]), "=&v"(vl[2]), "=&v"(vl[3]),
                  "=&v"(vl[4]), "=&v"(vl[5]), "=&v"(vl[6]), "=&v"(vl[7]),
                  "=&v"(vl[8]), "=&v"(vl[9]), "=&v"(vl[10]), "=&v"(vl[11]),
                  "=&v"(vl[12]), "=&v"(vl[13]), "=&v"(vl[14]), "=&v"(vl[15])
                : "v"(bL), "v"(bL + 4096), "v"(bL + 8192), "v"(bL + 12288),
                  "v"(bL + 16384), "v"(bL + 20480), "v"(bL + 24576), "v"(bL + 28672)
                : "memory");
            #pragma unroll
            for (int it = 0; it < 16; ++it) {
                *(unsigned long long*)&HaH[it][tid * 4] = vh[it];
                *(unsigned long long*)&HaL[it][tid * 4] = vl[it];
            }
        }
        // NO barrier: this wave reads only its own staged quarter.

        // ---- 3. MFMA over MY K-quarter, all 36 gate rows (3 nt-groups)
        f32x4 acc[3] = {};
        #pragma unroll
        for (int ks = 0; ks < 8; ++ks) {
            uint4 auh = *(const uint4*)&HaH[l15][wave * 256 + ks * 32 + l4 * 8];
            uint4 aul = *(const uint4*)&HaL[l15][wave * 256 + ks * 32 + l4 * 8];
            #pragma unroll
            for (int nt = 0; nt < 3; ++nt) {
                uint4 bl_ = *(const uint4*)&Wlo[wrow[nt]][wave * 256 + ks * 32 + l4 * 8];
                acc[nt] = __builtin_amdgcn_mfma_f32_16x16x32_bf16(
                        __builtin_bit_cast(bf16x8, auh), __builtin_bit_cast(bf16x8, bwh[nt][ks]), acc[nt], 0, 0, 0);
                acc[nt] = __builtin_amdgcn_mfma_f32_16x16x32_bf16(
                        __builtin_bit_cast(bf16x8, aul), __builtin_bit_cast(bf16x8, bwh[nt][ks]), acc[nt], 0, 0, 0);
                acc[nt] = __builtin_amdgcn_mfma_f32_16x16x32_bf16(
                        __builtin_bit_cast(bf16x8, auh), __builtin_bit_cast(bf16x8, bl_), acc[nt], 0, 0, 0);
            }
        }

        // ---- 4. cross-wave combine (C-frag: batch=l4*4+r, gate=nt*16+l15)
        float* pbuf = &pre[t & 1][0][0];
        #pragma unroll
        for (int nt = 0; nt < 3; ++nt) {
            #pragma unroll
            for (int r = 0; r < 4; ++r)
                unsafeAtomicAdd(pbuf + (l4 * 4 + r) * 52 + nt * 16 + l15, acc[nt][r]);
        }
        __syncthreads();   // [A] all quarters combined

        // ---- 5. epilogue (prefetched xg/xi/xo) + state update
        float gp0 = pre[t & 1][bl][col0]     + xg0;
        float gp1 = pre[t & 1][bl][col0 + 1] + xg1;
        float ip  = pre[t & 1][bl][32 + (col0 >> 4)] + xi;
        float op  = pre[t & 1][bl][34 + (col0 >> 4)] + xo;

        // zero the other buffer for step t+1 (separated from its adds by [B])
        float* nbuf = &pre[(t + 1) & 1][0][0];
        for (int i = tid; i < 16 * 52; i += 256) nbuf[i] = 0.f;

        float ig  = 1.f / (1.f + __expf(-ip));
        float og  = 1.f / (1.f + __expf(-op));
        cr0 += ig * tanhf(gp0);
        cr1 += ig * tanhf(gp1);
        float h0v = og * tanhf(cr0);
        float h1v = og * tanhf(cr1);

        // ---- 6. publish h_{t+1} (hi/lo planes, agent scope) -- critical path
        unsigned short h0h, h0l, h1h, h1l;
        split1(h0v, h0h, h0l); split1(h1v, h1h, h1l);
        size_t dsto = ((size_t)((t + 1) & 1) * B_ + Bg) * HOUT + hcol;
        __hip_atomic_store((unsigned int*)(hbH + dsto),
                           (unsigned)h0h | ((unsigned)h1h << 16),
                           __ATOMIC_RELAXED, __HIP_MEMORY_SCOPE_AGENT);
        __hip_atomic_store((unsigned int*)(hbL + dsto),
                           (unsigned)h0l | ((unsigned)h1l << 16),
                           __ATOMIC_RELAXED, __HIP_MEMORY_SCOPE_AGENT);

        asm volatile("s_waitcnt vmcnt(0)" ::: "memory");
        __syncthreads();   // [B] all publishes acked
        if (tid == 0)
            __hip_atomic_store(myflag, (unsigned)(t + 1),
                               __ATOMIC_RELAXED, __HIP_MEMORY_SCOPE_AGENT);

        // ---- 7. outputs + next-step prefetch (off the critical path)
        size_t ro = (size_t)Bg * S_ + t;
        c_out[(ro * NBLK + blkI) * DBLK + d0]     = cr0;
        c_out[(ro * NBLK + blkI) * DBLK + d0 + 1] = cr1;
        h_out[ro * HOUT + hcol]     = h0v;
        h_out[ro * HOUT + hcol + 1] = h1v;

        if (t + 1 < S_) {
            size_t rn = (size_t)Bg * S_ + (t + 1);
            xg0 = h_out[rn * HOUT + hcol];
            xg1 = h_out[rn * HOUT + hcol + 1];
            xi  = c_out[(rn * NBLK + blkI) * DBLK + 0];
            xo  = c_out[(rn * NBLK + blkI) * DBLK + 1];
        }
    }
}

// ---------------- launch ----------------
extern "C" void kernel_launch(void* const* d_in, const int* in_sizes, int n_in,
                              void* d_out, int out_size, void* d_ws, size_t ws_size,
                              hipStream_t stream) {
    const float* x  = (const float*)d_in[0];
    const float* h0 = (const float*)d_in[1];
    const float* c0 = (const float*)d_in[2];
    const float* Wi = (const float*)d_in[3];
    const float* bi = (const float*)d_in[4];
    const float* Wo = (const float*)d_in[5];
    const float* bo = (const float*)d_in[6];
    const float* Wg = (const float*)d_in[7];
    const float* bg = (const float*)d_in[8];
    const float* Ui = (const float*)d_in[9];
    const float* Uo = (const float*)d_in[10];
    const float* Ug = (const float*)d_in[11];

    float* c_out = (float*)d_out;
    float* h_out = c_out + (size_t)B_ * S_ * NBLK * DBLK;

    unsigned short* WsH  = (unsigned short*)d_ws;                    // [1152][1024]
    unsigned short* WsL  = WsH + (size_t)NGATE * HOUT;
    unsigned short* UsH  = WsL + (size_t)NGATE * HOUT;
    unsigned short* UsL  = UsH + (size_t)NGATE * HOUT;
    unsigned short* hbH  = UsL + (size_t)NGATE * HOUT;               // [2][32][1024]
    unsigned short* hbL  = hbH + (size_t)2 * B_ * HOUT;
    unsigned int*   flags = (unsigned int*)(hbL + (size_t)2 * B_ * HOUT); // [2][32]x128B

    hipMemsetAsync(flags, 0, 64 * 32 * sizeof(unsigned int), stream);
    k_init<<<2336, 256, 0, stream>>>(Wi, Wo, Wg, Ui, Uo, Ug, h0, WsH, WsL, UsH, UsL, hbH, hbL);
    k_gates<<<dim3((B_ * S_) / BM, NGATE / BN), 256, 0, stream>>>(
        x, WsH, WsL, bi, bo, bg, c_out, h_out);
    k_rec<<<64, 256, 0, stream>>>(c0, c_out, h_out, UsH, UsL, hbH, hbL, flags);
}

// Round 14
// 7056.258 us; speedup vs baseline: 1.1882x; 1.1882x over previous
//
#include <hip/hip_runtime.h>
#include <stdint.h>

#define B_    32
#define S_    1024
#define HIN   1024
#define NBLK  64
#define DBLK  16
#define HOUT  1024
#define NGATE 1152   // 64 i + 64 o + 1024 g
#define NSLICE 32    // gate slices (32 Ug rows + 2 Ui + 2 Uo each)

typedef __attribute__((ext_vector_type(8))) __bf16 bf16x8;
typedef __attribute__((ext_vector_type(4))) float  f32x4;

__device__ __forceinline__ unsigned short f2bf(float f) {
    union { float f; unsigned u; } v; v.f = f;
    return (unsigned short)((v.u + 0x7fffu + ((v.u >> 16) & 1u)) >> 16);
}
__device__ __forceinline__ float bf2f(unsigned short h) {
    union { unsigned u; float f; } v; v.u = ((unsigned)h) << 16; return v.f;
}
// fp32 -> hi+lo bf16 (v ~= hi + lo, residual <= 2^-18 |v|)
__device__ __forceinline__ void split1(float f, unsigned short& hi, unsigned short& lo) {
    hi = f2bf(f);
    lo = f2bf(f - bf2f(hi));
}

// gate-row mapping for a slice: rows 0..31 = Ug[slice*32+r], 32..33 = Ui[2s..], 34..35 = Uo[2s..]
__device__ __forceinline__ int slice_row(int slice, int r) {
    return (r < 32) ? (128 + slice * 32 + r)
         : (r < 34) ? (slice * 2 + (r - 32))
                    : (64 + slice * 2 + (r - 34));
}

// ---------------- phase 0: split W,U into hi/lo bf16; split h0 into planes ----------------
__global__ void k_init(const float* __restrict__ Wi, const float* __restrict__ Wo,
                       const float* __restrict__ Wg,
                       const float* __restrict__ Ui, const float* __restrict__ Uo,
                       const float* __restrict__ Ug, const float* __restrict__ h0,
                       unsigned short* __restrict__ WsH, unsigned short* __restrict__ WsL,
                       unsigned short* __restrict__ UsH, unsigned short* __restrict__ UsL,
                       unsigned short* __restrict__ hbH, unsigned short* __restrict__ hbL)
{
    int idx = blockIdx.x * 256 + threadIdx.x;
    const int nW = NGATE * HOUT / 4;           // 294912 quads per matrix set
    float4 v; unsigned short *dH, *dL;
    if (idx < nW) {
        int f = idx * 4; int row = f >> 10, k = f & 1023;
        const float* src = (row < 64)  ? (Wi + (size_t)row * HIN)
                         : (row < 128) ? (Wo + (size_t)(row - 64) * HIN)
                                       : (Wg + (size_t)(row - 128) * HIN);
        v = *(const float4*)(src + k);
        dH = WsH + f; dL = WsL + f;
    } else if (idx < 2 * nW) {
        int f = (idx - nW) * 4; int row = f >> 10, k = f & 1023;
        const float* src = (row < 64)  ? (Ui + (size_t)row * HOUT)
                         : (row < 128) ? (Uo + (size_t)(row - 64) * HOUT)
                                       : (Ug + (size_t)(row - 128) * HOUT);
        v = *(const float4*)(src + k);
        dH = UsH + f; dL = UsL + f;
    } else {
        int f = (idx - 2 * nW) * 4;
        if (f >= B_ * HOUT) return;
        v = *(const float4*)(h0 + f);
        dH = hbH + f; dL = hbL + f;            // slot 0
    }
    unsigned short th[4], tl[4];
    split1(v.x, th[0], tl[0]); split1(v.y, th[1], tl[1]);
    split1(v.z, th[2], tl[2]); split1(v.w, th[3], tl[3]);
    *(uint2*)dH = *(const uint2*)th;
    *(uint2*)dL = *(const uint2*)tl;
}

// ---------------- phase 1: gate pre-projection GEMM (bf16x3) ----------------
#define BM 128
#define BN 128
#define BK 32
#define LDP 56

__global__ __launch_bounds__(256) void k_gates(
    const float* __restrict__ x,
    const unsigned short* __restrict__ WsH, const unsigned short* __restrict__ WsL,
    const float* __restrict__ bi, const float* __restrict__ bo, const float* __restrict__ bg,
    float* __restrict__ c_out, float* __restrict__ h_out)
{
    __shared__ unsigned short AlH[BM][LDP], AlL[BM][LDP];
    __shared__ unsigned short BlH[BN][LDP], BlL[BN][LDP];
    const int tid  = threadIdx.x;
    const int bm   = blockIdx.x, bn = blockIdx.y;
    const int wave = tid >> 6,  lane = tid & 63;
    const int l15  = lane & 15, l4 = lane >> 4;
    const int wm   = wave >> 1, wn = wave & 1;
    const int rbase = tid >> 3;          // 0..31
    const int c4    = (tid & 7) * 4;     // 0..28

    f32x4 acc[4][4] = {};

    for (int kk = 0; kk < HIN; kk += BK) {
        #pragma unroll
        for (int i = 0; i < 4; ++i) {
            int row = rbase + 32 * i;
            float4 v = *(const float4*)(x + (size_t)(bm * BM + row) * HIN + kk + c4);
            unsigned short th[4], tl[4];
            split1(v.x, th[0], tl[0]); split1(v.y, th[1], tl[1]);
            split1(v.z, th[2], tl[2]); split1(v.w, th[3], tl[3]);
            *(uint2*)&AlH[row][c4] = *(const uint2*)th;
            *(uint2*)&AlL[row][c4] = *(const uint2*)tl;
            int n = bn * BN + row;
            *(uint2*)&BlH[row][c4] = *(const uint2*)(WsH + (size_t)n * HIN + kk + c4);
            *(uint2*)&BlL[row][c4] = *(const uint2*)(WsL + (size_t)n * HIN + kk + c4);
        }
        __syncthreads();
        uint4 ah[4], al[4], bh4[4], bl4[4];
        #pragma unroll
        for (int mi = 0; mi < 4; ++mi) {
            ah[mi] = *(const uint4*)&AlH[wm * 64 + mi * 16 + l15][l4 * 8];
            al[mi] = *(const uint4*)&AlL[wm * 64 + mi * 16 + l15][l4 * 8];
        }
        #pragma unroll
        for (int ni = 0; ni < 4; ++ni) {
            bh4[ni] = *(const uint4*)&BlH[wn * 64 + ni * 16 + l15][l4 * 8];
            bl4[ni] = *(const uint4*)&BlL[wn * 64 + ni * 16 + l15][l4 * 8];
        }
        #pragma unroll
        for (int mi = 0; mi < 4; ++mi) {
            #pragma unroll
            for (int ni = 0; ni < 4; ++ni) {
                acc[mi][ni] = __builtin_amdgcn_mfma_f32_16x16x32_bf16(
                    __builtin_bit_cast(bf16x8, ah[mi]), __builtin_bit_cast(bf16x8, bh4[ni]),
                    acc[mi][ni], 0, 0, 0);
                acc[mi][ni] = __builtin_amdgcn_mfma_f32_16x16x32_bf16(
                    __builtin_bit_cast(bf16x8, ah[mi]), __builtin_bit_cast(bf16x8, bl4[ni]),
                    acc[mi][ni], 0, 0, 0);
                acc[mi][ni] = __builtin_amdgcn_mfma_f32_16x16x32_bf16(
                    __builtin_bit_cast(bf16x8, al[mi]), __builtin_bit_cast(bf16x8, bh4[ni]),
                    acc[mi][ni], 0, 0, 0);
            }
        }
        __syncthreads();
    }

    #pragma unroll
    for (int ni = 0; ni < 4; ++ni) {
        int n = bn * BN + wn * 64 + ni * 16 + l15;
        float bv = (n < 64) ? bi[n] : (n < 128) ? bo[n - 64] : bg[n - 128];
        #pragma unroll
        for (int mi = 0; mi < 4; ++mi) {
            #pragma unroll
            for (int r = 0; r < 4; ++r) {
                int m = bm * BM + wm * 64 + mi * 16 + l4 * 4 + r;
                float val = acc[mi][ni][r] + bv;
                if (n >= 128) {
                    h_out[(size_t)m * HOUT + (n - 128)] = val;
                } else if (n < 64) {
                    c_out[((size_t)m * NBLK + n) * DBLK + 0] = val;
                } else {
                    c_out[((size_t)m * NBLK + (n - 64)) * DBLK + 1] = val;
                }
            }
        }
    }
}

// ---------------- phase 2: persistent lockstep recurrence (bf16x3) ----------------
// 64 WGs x 256 thr. slice = bid&31, group = bid>>5 (batches [16g,+16)).
// R14 = R13 with the NaN bug fixed: ALL 32 A-loads + the s_waitcnt vmcnt(0) live
// in ONE asm block, so every vh/vl consumer is data-dependent on a block that
// ENDS with the waitcnt (R13 split them across two blocks; register-only MFMA
// consumers of block-1 outputs were scheduled before block-2's waitcnt -> reads
// of undelivered VGPRs -> NaN. Skill rule #18.)
__global__ __launch_bounds__(256, 1) void k_rec(
    const float* __restrict__ c0,
    float* __restrict__ c_out, float* __restrict__ h_out,
    const unsigned short* __restrict__ UsH, const unsigned short* __restrict__ UsL,
    unsigned short* __restrict__ hbH, unsigned short* __restrict__ hbL,
    unsigned int* __restrict__ flags)
{
    __shared__ unsigned short Wlo[37][1032];   // 74.6 KB (row 36 = zeros)
    __shared__ float preW[4][16][52];          // 13.3 KB per-wave partials

    const int tid   = threadIdx.x;
    const int slice = blockIdx.x & 31;
    const int group = blockIdx.x >> 5;     // 0 or 1
    const int wave  = tid >> 6, lane = tid & 63;
    const int l15   = lane & 15, l4 = lane >> 4;

    // fill Wlo (lo-plane weights) into LDS; row 36 zeroed
    for (int idx = tid; idx < 37 * 128; idx += 256) {
        int row = idx >> 7, c8 = idx & 127;
        uint4 v = make_uint4(0, 0, 0, 0);
        if (row < 36)
            v = *(const uint4*)(UsL + (size_t)slice_row(slice, row) * HOUT + c8 * 8);
        *(uint4*)&Wlo[row][c8 * 8] = v;
    }

    // hi-plane B-fragments for this wave's K-quarter (compiler may stream from L2
    // each step -- R11/R12 showed that's fine)
    int wrow[3];
    uint4 bwh[3][8];
    #pragma unroll
    for (int nt = 0; nt < 3; ++nt) {
        int grow = nt * 16 + l15;
        bool valid = grow < 36;
        wrow[nt] = valid ? grow : 36;
        int srow = valid ? slice_row(slice, grow) : 0;
        const unsigned short* ph = UsH + (size_t)srow * HOUT + wave * 256 + l4 * 8;
        #pragma unroll
        for (int ks = 0; ks < 8; ++ks)
            bwh[nt][ks] = valid ? *(const uint4*)(ph + ks * 32) : make_uint4(0, 0, 0, 0);
    }

    // per-thread epilogue mapping: 2 consecutive h-cols
    const int e0   = tid * 2;
    const int bl   = e0 >> 5;             // 0..15 batch-in-group
    const int col0 = e0 & 31;             // even
    const int Bg   = group * 16 + bl;
    const int hcol = slice * 32 + col0;
    const int blkI = hcol >> 4, d0 = hcol & 15;
    float cr0 = c0[((size_t)Bg * NBLK + blkI) * DBLK + d0];
    float cr1 = c0[((size_t)Bg * NBLK + blkI) * DBLK + d0 + 1];

    unsigned int* flagbase = flags + (size_t)group * NSLICE * 32;
    unsigned int* myflag   = flagbase + slice * 32;                   // 128B apart
    unsigned int* pollfl   = flagbase + (lane & 31) * 32;

    // step-0 gate preactivation prefetch
    size_t rowoff = (size_t)Bg * S_;
    float xg0 = h_out[rowoff * HOUT + hcol];
    float xg1 = h_out[rowoff * HOUT + hcol + 1];
    float xi  = c_out[(rowoff * NBLK + blkI) * DBLK + 0];
    float xo  = c_out[(rowoff * NBLK + blkI) * DBLK + 1];

    __syncthreads();   // Wlo ready

    for (int t = 0; t < S_; ++t) {
        // ---- 1. poll (wave 0 only; lanes watch the 32 producer slices)
        if (t > 0) {
            if (wave == 0) {
                unsigned v;
                do {
                    v = __hip_atomic_load(pollfl, __ATOMIC_RELAXED, __HIP_MEMORY_SCOPE_AGENT);
                } while (!__all((int)(v >= (unsigned)t)));
            }
            __syncthreads();
        }

        // ---- 2. direct-to-register A loads for MY K-quarter: ONE asm block,
        //         32 loads + final vmcnt(0) so outputs are valid at block end.
        unsigned long long vh[16], vl[16];
        {
            const char* bH = (const char*)(hbH + ((size_t)(t & 1) * B_ + group * 16 + l15) * HOUT)
                           + wave * 512 + l4 * 16;
            const char* bL = (const char*)(hbL + ((size_t)(t & 1) * B_ + group * 16 + l15) * HOUT)
                           + wave * 512 + l4 * 16;
            asm volatile(
                "global_load_dwordx2 %0, %32, off sc0 sc1\n\t"
                "global_load_dwordx2 %1, %32, off offset:8 sc0 sc1\n\t"
                "global_load_dwordx2 %2, %32, off offset:64 sc0 sc1\n\t"
                "global_load_dwordx2 %3, %32, off offset:72 sc0 sc1\n\t"
                "global_load_dwordx2 %4, %32, off offset:128 sc0 sc1\n\t"
                "global_load_dwordx2 %5, %32, off offset:136 sc0 sc1\n\t"
                "global_load_dwordx2 %6, %32, off offset:192 sc0 sc1\n\t"
                "global_load_dwordx2 %7, %32, off offset:200 sc0 sc1\n\t"
                "global_load_dwordx2 %8, %32, off offset:256 sc0 sc1\n\t"
                "global_load_dwordx2 %9, %32, off offset:264 sc0 sc1\n\t"
                "global_load_dwordx2 %10, %32, off offset:320 sc0 sc1\n\t"
                "global_load_dwordx2 %11, %32, off offset:328 sc0 sc1\n\t"
                "global_load_dwordx2 %12, %32, off offset:384 sc0 sc1\n\t"
                "global_load_dwordx2 %13, %32, off offset:392 sc0 sc1\n\t"
                "global_load_dwordx2 %14, %32, off offset:448 sc0 sc1\n\t"
                "global_load_dwordx2 %15, %32, off offset:456 sc0 sc1\n\t"
                "global_load_dwordx2 %16, %33, off sc0 sc1\n\t"
                "global_load_dwordx2 %17, %33, off offset:8 sc0 sc1\n\t"
                "global_load_dwordx2 %18, %33, off offset:64 sc0 sc1\n\t"
                "global_load_dwordx2 %19, %33, off offset:72 sc0 sc1\n\t"
                "global_load_dwordx2 %20, %33, off offset:128 sc0 sc1\n\t"
                "global_load_dwordx2 %21, %33, off offset:136 sc0 sc1\n\t"
                "global_load_dwordx2 %22, %33, off offset:192 sc0 sc1\n\t"
                "global_load_dwordx2 %23, %33, off offset:200 sc0 sc1\n\t"
                "global_load_dwordx2 %24, %33, off offset:256 sc0 sc1\n\t"
                "global_load_dwordx2 %25, %33, off offset:264 sc0 sc1\n\t"
                "global_load_dwordx2 %26, %33, off offset:320 sc0 sc1\n\t"
                "global_load_dwordx2 %27, %33, off offset:328 sc0 sc1\n\t"
                "global_load_dwordx2 %28, %33, off offset:384 sc0 sc1\n\t"
                "global_load_dwordx2 %29, %33, off offset:392 sc0 sc1\n\t"
                "global_load_dwordx2 %30, %33, off offset:448 sc0 sc1\n\t"
                "global_load_dwordx2 %31, %33, off offset:456 sc0 sc1\n\t"
                "s_waitcnt vmcnt(0)\n\t"
                : "=&v"(vh[0]), "=&v"(vh[1]), "=&v"(vh[2]), "=&v"(vh[3]),
                  "=&v"(vh[4]), "=&v"(vh[5]), "=&v"(vh[6]), "=&v"(vh[7]),
                  "=&v"(vh[8]), "=&v"(vh[9]), "=&v"(vh[10]), "=&v"(vh[11]),
                  "=&v"(vh[12]), "=&v"(vh[13]), "=&v"(vh[14]), "=&v"(vh[15]),
                  "=&v"(vl[0]), "=&v"(vl[1]), "=&v"(vl[2]), "=&v"(vl[3]),
                  "=&v"(vl[4]), "=&v"(vl[5]), "=&v"(vl[6]), "=&v"(vl[7]),
                  "=&v"(vl[8]), "=&v"(vl[9]), "=&v"(vl[10]), "=&v"(vl[11]),
                  "=&v"(vl[12]), "=&v"(vl[13]), "=&v"(vl[14]), "=&v"(vl[15])
                : "v"(bH), "v"(bL)
                : "memory");
            __builtin_amdgcn_sched_barrier(0);
        }

        // ---- 3. MFMA over MY K-quarter, all 36 gate rows (3 nt-groups)
        f32x4 acc[3] = {};
        #pragma unroll
        for (int ks = 0; ks < 8; ++ks) {
            uint4 auh = make_uint4((unsigned)vh[2 * ks], (unsigned)(vh[2 * ks] >> 32),
                                   (unsigned)vh[2 * ks + 1], (unsigned)(vh[2 * ks + 1] >> 32));
            uint4 aul = make_uint4((unsigned)vl[2 * ks], (unsigned)(vl[2 * ks] >> 32),
                                   (unsigned)vl[2 * ks + 1], (unsigned)(vl[2 * ks + 1] >> 32));
            #pragma unroll
            for (int nt = 0; nt < 3; ++nt) {
                uint4 bl_ = *(const uint4*)&Wlo[wrow[nt]][wave * 256 + ks * 32 + l4 * 8];
                acc[nt] = __builtin_amdgcn_mfma_f32_16x16x32_bf16(
                        __builtin_bit_cast(bf16x8, auh), __builtin_bit_cast(bf16x8, bwh[nt][ks]), acc[nt], 0, 0, 0);
                acc[nt] = __builtin_amdgcn_mfma_f32_16x16x32_bf16(
                        __builtin_bit_cast(bf16x8, aul), __builtin_bit_cast(bf16x8, bwh[nt][ks]), acc[nt], 0, 0, 0);
                acc[nt] = __builtin_amdgcn_mfma_f32_16x16x32_bf16(
                        __builtin_bit_cast(bf16x8, auh), __builtin_bit_cast(bf16x8, bl_), acc[nt], 0, 0, 0);
            }
        }

        // ---- 4. per-wave partials to LDS (plain writes; every cell written)
        #pragma unroll
        for (int nt = 0; nt < 3; ++nt) {
            #pragma unroll
            for (int r = 0; r < 4; ++r)
                preW[wave][l4 * 4 + r][nt * 16 + l15] = acc[nt][r];
        }
        __syncthreads();   // [A] all quarters in LDS

        // ---- 5. epilogue: sum the 4 wave-partials + prefetched xg/xi/xo
        float gp0 = xg0, gp1 = xg1, ip = xi, op = xo;
        #pragma unroll
        for (int w = 0; w < 4; ++w) {
            gp0 += preW[w][bl][col0];
            gp1 += preW[w][bl][col0 + 1];
            ip  += preW[w][bl][32 + (col0 >> 4)];
            op  += preW[w][bl][34 + (col0 >> 4)];
        }
        float ig  = 1.f / (1.f + __expf(-ip));
        float og  = 1.f / (1.f + __expf(-op));
        cr0 += ig * tanhf(gp0);
        cr1 += ig * tanhf(gp1);
        float h0v = og * tanhf(cr0);
        float h1v = og * tanhf(cr1);

        // ---- 6. publish h_{t+1} (hi/lo planes, agent scope) -- critical path
        unsigned short h0h, h0l, h1h, h1l;
        split1(h0v, h0h, h0l); split1(h1v, h1h, h1l);
        size_t dsto = ((size_t)((t + 1) & 1) * B_ + Bg) * HOUT + hcol;
        __hip_atomic_store((unsigned int*)(hbH + dsto),
                           (unsigned)h0h | ((unsigned)h1h << 16),
                           __ATOMIC_RELAXED, __HIP_MEMORY_SCOPE_AGENT);
        __hip_atomic_store((unsigned int*)(hbL + dsto),
                           (unsigned)h0l | ((unsigned)h1l << 16),
                           __ATOMIC_RELAXED, __HIP_MEMORY_SCOPE_AGENT);

        asm volatile("s_waitcnt vmcnt(0)" ::: "memory");
        __syncthreads();   // [B] all publishes acked
        if (tid == 0)
            __hip_atomic_store(myflag, (unsigned)(t + 1),
                               __ATOMIC_RELAXED, __HIP_MEMORY_SCOPE_AGENT);

        // ---- 7. outputs + next-step prefetch (off the critical path)
        size_t ro = (size_t)Bg * S_ + t;
        c_out[(ro * NBLK + blkI) * DBLK + d0]     = cr0;
        c_out[(ro * NBLK + blkI) * DBLK + d0 + 1] = cr1;
        h_out[ro * HOUT + hcol]     = h0v;
        h_out[ro * HOUT + hcol + 1] = h1v;

        if (t + 1 < S_) {
            size_t rn = (size_t)Bg * S_ + (t + 1);
            xg0 = h_out[rn * HOUT + hcol];
            xg1 = h_out[rn * HOUT + hcol + 1];
            xi  = c_out[(rn * NBLK + blkI) * DBLK + 0];
            xo  = c_out[(rn * NBLK + blkI) * DBLK + 1];
        }
    }
}

// ---------------- launch ----------------
extern "C" void kernel_launch(void* const* d_in, const int* in_sizes, int n_in,
                              void* d_out, int out_size, void* d_ws, size_t ws_size,
                              hipStream_t stream) {
    const float* x  = (const float*)d_in[0];
    const float* h0 = (const float*)d_in[1];
    const float* c0 = (const float*)d_in[2];
    const float* Wi = (const float*)d_in[3];
    const float* bi = (const float*)d_in[4];
    const float* Wo = (const float*)d_in[5];
    const float* bo = (const float*)d_in[6];
    const float* Wg = (const float*)d_in[7];
    const float* bg = (const float*)d_in[8];
    const float* Ui = (const float*)d_in[9];
    const float* Uo = (const float*)d_in[10];
    const float* Ug = (const float*)d_in[11];

    float* c_out = (float*)d_out;
    float* h_out = c_out + (size_t)B_ * S_ * NBLK * DBLK;

    unsigned short* WsH  = (unsigned short*)d_ws;                    // [1152][1024]
    unsigned short* WsL  = WsH + (size_t)NGATE * HOUT;
    unsigned short* UsH  = WsL + (size_t)NGATE * HOUT;
    unsigned short* UsL  = UsH + (size_t)NGATE * HOUT;
    unsigned short* hbH  = UsL + (size_t)NGATE * HOUT;               // [2][32][1024]
    unsigned short* hbL  = hbH + (size_t)2 * B_ * HOUT;
    unsigned int*   flags = (unsigned int*)(hbL + (size_t)2 * B_ * HOUT); // [2][32]x128B

    hipMemsetAsync(flags, 0, 64 * 32 * sizeof(unsigned int), stream);
    k_init<<<2336, 256, 0, stream>>>(Wi, Wo, Wg, Ui, Uo, Ug, h0, WsH, WsL, UsH, UsL, hbH, hbL);
    k_gates<<<dim3((B_ * S_) / BM, NGATE / BN), 256, 0, stream>>>(
        x, WsH, WsL, bi, bo, bg, c_out, h_out);
    k_rec<<<64, 256, 0, stream>>>(c0, c_out, h_out, UsH, UsL, hbH, hbL, flags);
}

// Round 15
// 4979.217 us; speedup vs baseline: 1.6838x; 1.4171x over previous
//
#include <hip/hip_runtime.h>
#include <stdint.h>

#define B_    32
#define S_    1024
#define HIN   1024
#define NBLK  64
#define DBLK  16
#define HOUT  1024
#define NGATE 1152   // 64 i + 64 o + 1024 g
#define NSLICE 32    // gate slices (32 Ug rows + 2 Ui + 2 Uo each)

typedef __attribute__((ext_vector_type(8))) __bf16 bf16x8;
typedef __attribute__((ext_vector_type(4))) float  f32x4;

__device__ __forceinline__ unsigned short f2bf(float f) {
    union { float f; unsigned u; } v; v.f = f;
    return (unsigned short)((v.u + 0x7fffu + ((v.u >> 16) & 1u)) >> 16);
}
__device__ __forceinline__ float bf2f(unsigned short h) {
    union { unsigned u; float f; } v; v.u = ((unsigned)h) << 16; return v.f;
}
// fp32 -> hi+lo bf16 (v ~= hi + lo, residual <= 2^-18 |v|)
__device__ __forceinline__ void split1(float f, unsigned short& hi, unsigned short& lo) {
    hi = f2bf(f);
    lo = f2bf(f - bf2f(hi));
}

// gate-row mapping for a slice: rows 0..31 = Ug[slice*32+r], 32..33 = Ui[2s..], 34..35 = Uo[2s..]
__device__ __forceinline__ int slice_row(int slice, int r) {
    return (r < 32) ? (128 + slice * 32 + r)
         : (r < 34) ? (slice * 2 + (r - 32))
                    : (64 + slice * 2 + (r - 34));
}

// ---------------- phase 0: split W,U into hi/lo bf16; split h0 into planes ----------------
__global__ void k_init(const float* __restrict__ Wi, const float* __restrict__ Wo,
                       const float* __restrict__ Wg,
                       const float* __restrict__ Ui, const float* __restrict__ Uo,
                       const float* __restrict__ Ug, const float* __restrict__ h0,
                       unsigned short* __restrict__ WsH, unsigned short* __restrict__ WsL,
                       unsigned short* __restrict__ UsH, unsigned short* __restrict__ UsL,
                       unsigned short* __restrict__ hbH, unsigned short* __restrict__ hbL)
{
    int idx = blockIdx.x * 256 + threadIdx.x;
    const int nW = NGATE * HOUT / 4;           // 294912 quads per matrix set
    float4 v; unsigned short *dH, *dL;
    if (idx < nW) {
        int f = idx * 4; int row = f >> 10, k = f & 1023;
        const float* src = (row < 64)  ? (Wi + (size_t)row * HIN)
                         : (row < 128) ? (Wo + (size_t)(row - 64) * HIN)
                                       : (Wg + (size_t)(row - 128) * HIN);
        v = *(const float4*)(src + k);
        dH = WsH + f; dL = WsL + f;
    } else if (idx < 2 * nW) {
        int f = (idx - nW) * 4; int row = f >> 10, k = f & 1023;
        const float* src = (row < 64)  ? (Ui + (size_t)row * HOUT)
                         : (row < 128) ? (Uo + (size_t)(row - 64) * HOUT)
                                       : (Ug + (size_t)(row - 128) * HOUT);
        v = *(const float4*)(src + k);
        dH = UsH + f; dL = UsL + f;
    } else {
        int f = (idx - 2 * nW) * 4;
        if (f >= B_ * HOUT) return;
        v = *(const float4*)(h0 + f);
        dH = hbH + f; dL = hbL + f;            // slot 0
    }
    unsigned short th[4], tl[4];
    split1(v.x, th[0], tl[0]); split1(v.y, th[1], tl[1]);
    split1(v.z, th[2], tl[2]); split1(v.w, th[3], tl[3]);
    *(uint2*)dH = *(const uint2*)th;
    *(uint2*)dL = *(const uint2*)tl;
}

// ---------------- phase 1: gate pre-projection GEMM (bf16x3) ----------------
#define BM 128
#define BN 128
#define BK 32
#define LDP 56

__global__ __launch_bounds__(256) void k_gates(
    const float* __restrict__ x,
    const unsigned short* __restrict__ WsH, const unsigned short* __restrict__ WsL,
    const float* __restrict__ bi, const float* __restrict__ bo, const float* __restrict__ bg,
    float* __restrict__ c_out, float* __restrict__ h_out)
{
    __shared__ unsigned short AlH[BM][LDP], AlL[BM][LDP];
    __shared__ unsigned short BlH[BN][LDP], BlL[BN][LDP];
    const int tid  = threadIdx.x;
    const int bm   = blockIdx.x, bn = blockIdx.y;
    const int wave = tid >> 6,  lane = tid & 63;
    const int l15  = lane & 15, l4 = lane >> 4;
    const int wm   = wave >> 1, wn = wave & 1;
    const int rbase = tid >> 3;          // 0..31
    const int c4    = (tid & 7) * 4;     // 0..28

    f32x4 acc[4][4] = {};

    for (int kk = 0; kk < HIN; kk += BK) {
        #pragma unroll
        for (int i = 0; i < 4; ++i) {
            int row = rbase + 32 * i;
            float4 v = *(const float4*)(x + (size_t)(bm * BM + row) * HIN + kk + c4);
            unsigned short th[4], tl[4];
            split1(v.x, th[0], tl[0]); split1(v.y, th[1], tl[1]);
            split1(v.z, th[2], tl[2]); split1(v.w, th[3], tl[3]);
            *(uint2*)&AlH[row][c4] = *(const uint2*)th;
            *(uint2*)&AlL[row][c4] = *(const uint2*)tl;
            int n = bn * BN + row;
            *(uint2*)&BlH[row][c4] = *(const uint2*)(WsH + (size_t)n * HIN + kk + c4);
            *(uint2*)&BlL[row][c4] = *(const uint2*)(WsL + (size_t)n * HIN + kk + c4);
        }
        __syncthreads();
        uint4 ah[4], al[4], bh4[4], bl4[4];
        #pragma unroll
        for (int mi = 0; mi < 4; ++mi) {
            ah[mi] = *(const uint4*)&AlH[wm * 64 + mi * 16 + l15][l4 * 8];
            al[mi] = *(const uint4*)&AlL[wm * 64 + mi * 16 + l15][l4 * 8];
        }
        #pragma unroll
        for (int ni = 0; ni < 4; ++ni) {
            bh4[ni] = *(const uint4*)&BlH[wn * 64 + ni * 16 + l15][l4 * 8];
            bl4[ni] = *(const uint4*)&BlL[wn * 64 + ni * 16 + l15][l4 * 8];
        }
        #pragma unroll
        for (int mi = 0; mi < 4; ++mi) {
            #pragma unroll
            for (int ni = 0; ni < 4; ++ni) {
                acc[mi][ni] = __builtin_amdgcn_mfma_f32_16x16x32_bf16(
                    __builtin_bit_cast(bf16x8, ah[mi]), __builtin_bit_cast(bf16x8, bh4[ni]),
                    acc[mi][ni], 0, 0, 0);
                acc[mi][ni] = __builtin_amdgcn_mfma_f32_16x16x32_bf16(
                    __builtin_bit_cast(bf16x8, ah[mi]), __builtin_bit_cast(bf16x8, bl4[ni]),
                    acc[mi][ni], 0, 0, 0);
                acc[mi][ni] = __builtin_amdgcn_mfma_f32_16x16x32_bf16(
                    __builtin_bit_cast(bf16x8, al[mi]), __builtin_bit_cast(bf16x8, bh4[ni]),
                    acc[mi][ni], 0, 0, 0);
            }
        }
        __syncthreads();
    }

    #pragma unroll
    for (int ni = 0; ni < 4; ++ni) {
        int n = bn * BN + wn * 64 + ni * 16 + l15;
        float bv = (n < 64) ? bi[n] : (n < 128) ? bo[n - 64] : bg[n - 128];
        #pragma unroll
        for (int mi = 0; mi < 4; ++mi) {
            #pragma unroll
            for (int r = 0; r < 4; ++r) {
                int m = bm * BM + wm * 64 + mi * 16 + l4 * 4 + r;
                float val = acc[mi][ni][r] + bv;
                if (n >= 128) {
                    h_out[(size_t)m * HOUT + (n - 128)] = val;
                } else if (n < 64) {
                    c_out[((size_t)m * NBLK + n) * DBLK + 0] = val;
                } else {
                    c_out[((size_t)m * NBLK + (n - 64)) * DBLK + 1] = val;
                }
            }
        }
    }
}

// ---------------- phase 2: persistent lockstep recurrence (bf16x3) ----------------
// 64 WGs x 256 thr. slice = bid&31, group = bid>>5 (batches [16g,+16)).
// R15 = measured-best composite:
//  * R11 staging verbatim (coalesced asm bulk loads -> LDS; wave w's tid-range
//    stages exactly its K-quarter -> NO post-stage barrier, R12-verified)
//  * K-split MFMA reads (wave w computes all 36 gate rows over K-quarter
//    [256w,+256)): LDS reads 288 -> 160 b128/WG/step
//  * preW[4] plain-write combine (R14-verified), epilogue sums 4 partials
//  * poll de-poison: next-step prefetch issued EARLY (hides under stage drain),
//    outputs folded into [B] drain (L2-ack, ~free), flag stored by tid 64 so
//    the polling wave has ZERO outstanding VMEM at poll time
__global__ __launch_bounds__(256, 1) void k_rec(
    const float* __restrict__ c0,
    float* __restrict__ c_out, float* __restrict__ h_out,
    const unsigned short* __restrict__ UsH, const unsigned short* __restrict__ UsL,
    unsigned short* __restrict__ hbH, unsigned short* __restrict__ hbL,
    unsigned int* __restrict__ flags)
{
    __shared__ unsigned short Wlo[37][1032];   // 74.6 KB (row 36 = zeros)
    __shared__ unsigned short HaH[16][1032];   // 33 KB
    __shared__ unsigned short HaL[16][1032];   // 33 KB
    __shared__ float preW[4][16][53];          // 13.6 KB per-wave partials (pad 53)

    const int tid   = threadIdx.x;
    const int slice = blockIdx.x & 31;
    const int group = blockIdx.x >> 5;     // 0 or 1
    const int wave  = tid >> 6, lane = tid & 63;
    const int l15   = lane & 15, l4 = lane >> 4;

    // fill Wlo (lo-plane weights) into LDS; row 36 zeroed
    for (int idx = tid; idx < 37 * 128; idx += 256) {
        int row = idx >> 7, c8 = idx & 127;
        uint4 v = make_uint4(0, 0, 0, 0);
        if (row < 36)
            v = *(const uint4*)(UsL + (size_t)slice_row(slice, row) * HOUT + c8 * 8);
        *(uint4*)&Wlo[row][c8 * 8] = v;
    }

    // hi-plane B-fragments for this wave's K-quarter (L2-streamed by compiler; OK)
    int wrow[3];
    uint4 bwh[3][8];
    #pragma unroll
    for (int nt = 0; nt < 3; ++nt) {
        int grow = nt * 16 + l15;
        bool valid = grow < 36;
        wrow[nt] = valid ? grow : 36;
        int srow = valid ? slice_row(slice, grow) : 0;
        const unsigned short* ph = UsH + (size_t)srow * HOUT + wave * 256 + l4 * 8;
        #pragma unroll
        for (int ks = 0; ks < 8; ++ks)
            bwh[nt][ks] = valid ? *(const uint4*)(ph + ks * 32) : make_uint4(0, 0, 0, 0);
    }

    // per-thread epilogue mapping: 2 consecutive h-cols
    const int e0   = tid * 2;
    const int bl   = e0 >> 5;             // 0..15 batch-in-group
    const int col0 = e0 & 31;             // even
    const int Bg   = group * 16 + bl;
    const int hcol = slice * 32 + col0;
    const int blkI = hcol >> 4, d0 = hcol & 15;
    float cr0 = c0[((size_t)Bg * NBLK + blkI) * DBLK + d0];
    float cr1 = c0[((size_t)Bg * NBLK + blkI) * DBLK + d0 + 1];

    unsigned int* flagbase = flags + (size_t)group * NSLICE * 32;
    unsigned int* myflag   = flagbase + slice * 32;                   // 128B apart
    unsigned int* pollfl   = flagbase + (lane & 31) * 32;

    // step-0 gate preactivation prefetch
    float xg0, xg1, xi, xo;
    {
        size_t r0 = (size_t)Bg * S_;
        xg0 = h_out[r0 * HOUT + hcol];
        xg1 = h_out[r0 * HOUT + hcol + 1];
        xi  = c_out[(r0 * NBLK + blkI) * DBLK + 0];
        xo  = c_out[(r0 * NBLK + blkI) * DBLK + 1];
    }

    __syncthreads();   // Wlo ready

    for (int t = 0; t < S_; ++t) {
        // ---- 1. poll (wave 0 only; zero outstanding VMEM in this wave -> clean)
        if (t > 0) {
            if (wave == 0) {
                unsigned v;
                do {
                    v = __hip_atomic_load(pollfl, __ATOMIC_RELAXED, __HIP_MEMORY_SCOPE_AGENT);
                } while (!__all((int)(v >= (unsigned)t)));
            }
            __syncthreads();
        }

        // ---- 2. EARLY next-step prefetch: HBM latency hides under the stage drain
        float nxg0 = 0.f, nxg1 = 0.f, nxi = 0.f, nxo = 0.f;
        if (t + 1 < S_) {
            size_t rn = (size_t)Bg * S_ + (t + 1);
            nxg0 = h_out[rn * HOUT + hcol];
            nxg1 = h_out[rn * HOUT + hcol + 1];
            nxi  = c_out[(rn * NBLK + blkI) * DBLK + 0];
            nxo  = c_out[(rn * NBLK + blkI) * DBLK + 1];
        }

        // ---- 3. bulk-stage h_t hi/lo planes (R11 asm verbatim): 32 coherent loads
        //         in flight, ONE drain. thread tid covers col-chunk tid*8B of all
        //         16 rows -> wave w stages exactly its K-quarter.
        {
            const char* bH = (const char*)(hbH + ((size_t)(t & 1) * B_ + group * 16) * HOUT) + tid * 8;
            const char* bL = (const char*)(hbL + ((size_t)(t & 1) * B_ + group * 16) * HOUT) + tid * 8;
            unsigned long long vh[16], vl[16];
            asm volatile(
                "global_load_dwordx2 %0, %32, off sc0 sc1\n\t"
                "global_load_dwordx2 %1, %32, off offset:2048 sc0 sc1\n\t"
                "global_load_dwordx2 %2, %33, off sc0 sc1\n\t"
                "global_load_dwordx2 %3, %33, off offset:2048 sc0 sc1\n\t"
                "global_load_dwordx2 %4, %34, off sc0 sc1\n\t"
                "global_load_dwordx2 %5, %34, off offset:2048 sc0 sc1\n\t"
                "global_load_dwordx2 %6, %35, off sc0 sc1\n\t"
                "global_load_dwordx2 %7, %35, off offset:2048 sc0 sc1\n\t"
                "global_load_dwordx2 %8, %36, off sc0 sc1\n\t"
                "global_load_dwordx2 %9, %36, off offset:2048 sc0 sc1\n\t"
                "global_load_dwordx2 %10, %37, off sc0 sc1\n\t"
                "global_load_dwordx2 %11, %37, off offset:2048 sc0 sc1\n\t"
                "global_load_dwordx2 %12, %38, off sc0 sc1\n\t"
                "global_load_dwordx2 %13, %38, off offset:2048 sc0 sc1\n\t"
                "global_load_dwordx2 %14, %39, off sc0 sc1\n\t"
                "global_load_dwordx2 %15, %39, off offset:2048 sc0 sc1\n\t"
                "global_load_dwordx2 %16, %40, off sc0 sc1\n\t"
                "global_load_dwordx2 %17, %40, off offset:2048 sc0 sc1\n\t"
                "global_load_dwordx2 %18, %41, off sc0 sc1\n\t"
                "global_load_dwordx2 %19, %41, off offset:2048 sc0 sc1\n\t"
                "global_load_dwordx2 %20, %42, off sc0 sc1\n\t"
                "global_load_dwordx2 %21, %42, off offset:2048 sc0 sc1\n\t"
                "global_load_dwordx2 %22, %43, off sc0 sc1\n\t"
                "global_load_dwordx2 %23, %43, off offset:2048 sc0 sc1\n\t"
                "global_load_dwordx2 %24, %44, off sc0 sc1\n\t"
                "global_load_dwordx2 %25, %44, off offset:2048 sc0 sc1\n\t"
                "global_load_dwordx2 %26, %45, off sc0 sc1\n\t"
                "global_load_dwordx2 %27, %45, off offset:2048 sc0 sc1\n\t"
                "global_load_dwordx2 %28, %46, off sc0 sc1\n\t"
                "global_load_dwordx2 %29, %46, off offset:2048 sc0 sc1\n\t"
                "global_load_dwordx2 %30, %47, off sc0 sc1\n\t"
                "global_load_dwordx2 %31, %47, off offset:2048 sc0 sc1\n\t"
                "s_waitcnt vmcnt(0)\n\t"
                : "=&v"(vh[0]), "=&v"(vh[1]), "=&v"(vh[2]), "=&v"(vh[3]),
                  "=&v"(vh[4]), "=&v"(vh[5]), "=&v"(vh[6]), "=&v"(vh[7]),
                  "=&v"(vh[8]), "=&v"(vh[9]), "=&v"(vh[10]), "=&v"(vh[11]),
                  "=&v"(vh[12]), "=&v"(vh[13]), "=&v"(vh[14]), "=&v"(vh[15]),
                  "=&v"(vl[0]), "=&v"(vl[1]), "=&v"(vl[2]), "=&v"(vl[3]),
                  "=&v"(vl[4]), "=&v"(vl[5]), "=&v"(vl[6]), "=&v"(vl[7]),
                  "=&v"(vl[8]), "=&v"(vl[9]), "=&v"(vl[10]), "=&v"(vl[11]),
                  "=&v"(vl[12]), "=&v"(vl[13]), "=&v"(vl[14]), "=&v"(vl[15])
                : "v"(bH), "v"(bH + 4096), "v"(bH + 8192), "v"(bH + 12288),
                  "v"(bH + 16384), "v"(bH + 20480), "v"(bH + 24576), "v"(bH + 28672),
                  "v"(bL), "v"(bL + 4096), "v"(bL + 8192), "v"(bL + 12288),
                  "v"(bL + 16384), "v"(bL + 20480), "v"(bL + 24576), "v"(bL + 28672)
                : "memory");
            #pragma unroll
            for (int it = 0; it < 16; ++it) {
                *(unsigned long long*)&HaH[it][tid * 4] = vh[it];
                *(unsigned long long*)&HaL[it][tid * 4] = vl[it];
            }
        }
        // NO barrier: this wave reads only its own staged K-quarter.

        // ---- 4. K-split MFMA: all 36 gate rows over MY quarter (A from LDS)
        f32x4 acc[3] = {};
        #pragma unroll
        for (int ks = 0; ks < 8; ++ks) {
            uint4 auh = *(const uint4*)&HaH[l15][wave * 256 + ks * 32 + l4 * 8];
            uint4 aul = *(const uint4*)&HaL[l15][wave * 256 + ks * 32 + l4 * 8];
            #pragma unroll
            for (int nt = 0; nt < 3; ++nt) {
                uint4 bl_ = *(const uint4*)&Wlo[wrow[nt]][wave * 256 + ks * 32 + l4 * 8];
                acc[nt] = __builtin_amdgcn_mfma_f32_16x16x32_bf16(
                        __builtin_bit_cast(bf16x8, auh), __builtin_bit_cast(bf16x8, bwh[nt][ks]), acc[nt], 0, 0, 0);
                acc[nt] = __builtin_amdgcn_mfma_f32_16x16x32_bf16(
                        __builtin_bit_cast(bf16x8, aul), __builtin_bit_cast(bf16x8, bwh[nt][ks]), acc[nt], 0, 0, 0);
                acc[nt] = __builtin_amdgcn_mfma_f32_16x16x32_bf16(
                        __builtin_bit_cast(bf16x8, auh), __builtin_bit_cast(bf16x8, bl_), acc[nt], 0, 0, 0);
            }
        }

        // ---- 5. per-wave partials to LDS (plain writes; every cell written)
        #pragma unroll
        for (int nt = 0; nt < 3; ++nt) {
            #pragma unroll
            for (int r = 0; r < 4; ++r)
                preW[wave][l4 * 4 + r][nt * 16 + l15] = acc[nt][r];
        }
        __syncthreads();   // [A] all quarters in LDS

        // ---- 6. epilogue: sum 4 wave-partials + prefetched xg/xi/xo
        float gp0 = xg0, gp1 = xg1, ip = xi, op = xo;
        #pragma unroll
        for (int w = 0; w < 4; ++w) {
            gp0 += preW[w][bl][col0];
            gp1 += preW[w][bl][col0 + 1];
            ip  += preW[w][bl][32 + (col0 >> 4)];
            op  += preW[w][bl][34 + (col0 >> 4)];
        }
        float ig  = 1.f / (1.f + __expf(-ip));
        float og  = 1.f / (1.f + __expf(-op));
        cr0 += ig * tanhf(gp0);
        cr1 += ig * tanhf(gp1);
        float h0v = og * tanhf(cr0);
        float h1v = og * tanhf(cr1);

        // ---- 7. publish h_{t+1} (LLC) + outputs (L2-ack): one combined drain
        unsigned short h0h, h0l, h1h, h1l;
        split1(h0v, h0h, h0l); split1(h1v, h1h, h1l);
        size_t dsto = ((size_t)((t + 1) & 1) * B_ + Bg) * HOUT + hcol;
        __hip_atomic_store((unsigned int*)(hbH + dsto),
                           (unsigned)h0h | ((unsigned)h1h << 16),
                           __ATOMIC_RELAXED, __HIP_MEMORY_SCOPE_AGENT);
        __hip_atomic_store((unsigned int*)(hbL + dsto),
                           (unsigned)h0l | ((unsigned)h1l << 16),
                           __ATOMIC_RELAXED, __HIP_MEMORY_SCOPE_AGENT);

        size_t ro = (size_t)Bg * S_ + t;
        c_out[(ro * NBLK + blkI) * DBLK + d0]     = cr0;
        c_out[(ro * NBLK + blkI) * DBLK + d0 + 1] = cr1;
        h_out[ro * HOUT + hcol]     = h0v;
        h_out[ro * HOUT + hcol + 1] = h1v;

        asm volatile("s_waitcnt vmcnt(0)" ::: "memory");
        __syncthreads();   // [B] publishes + outputs acked; nothing outstanding
        if (tid == 64)     // flag from wave 1: keeps the POLLING wave VMEM-clean
            __hip_atomic_store(myflag, (unsigned)(t + 1),
                               __ATOMIC_RELAXED, __HIP_MEMORY_SCOPE_AGENT);

        // ---- 8. rotate prefetched gate preactivations
        xg0 = nxg0; xg1 = nxg1; xi = nxi; xo = nxo;
    }
}

// ---------------- launch ----------------
extern "C" void kernel_launch(void* const* d_in, const int* in_sizes, int n_in,
                              void* d_out, int out_size, void* d_ws, size_t ws_size,
                              hipStream_t stream) {
    const float* x  = (const float*)d_in[0];
    const float* h0 = (const float*)d_in[1];
    const float* c0 = (const float*)d_in[2];
    const float* Wi = (const float*)d_in[3];
    const float* bi = (const float*)d_in[4];
    const float* Wo = (const float*)d_in[5];
    const float* bo = (const float*)d_in[6];
    const float* Wg = (const float*)d_in[7];
    const float* bg = (const float*)d_in[8];
    const float* Ui = (const float*)d_in[9];
    const float* Uo = (const float*)d_in[10];
    const float* Ug = (const float*)d_in[11];

    float* c_out = (float*)d_out;
    float* h_out = c_out + (size_t)B_ * S_ * NBLK * DBLK;

    unsigned short* WsH  = (unsigned short*)d_ws;                    // [1152][1024]
    unsigned short* WsL  = WsH + (size_t)NGATE * HOUT;
    unsigned short* UsH  = WsL + (size_t)NGATE * HOUT;
    unsigned short* UsL  = UsH + (size_t)NGATE * HOUT;
    unsigned short* hbH  = UsL + (size_t)NGATE * HOUT;               // [2][32][1024]
    unsigned short* hbL  = hbH + (size_t)2 * B_ * HOUT;
    unsigned int*   flags = (unsigned int*)(hbL + (size_t)2 * B_ * HOUT); // [2][32]x128B

    hipMemsetAsync(flags, 0, 64 * 32 * sizeof(unsigned int), stream);
    k_init<<<2336, 256, 0, stream>>>(Wi, Wo, Wg, Ui, Uo, Ug, h0, WsH, WsL, UsH, UsL, hbH, hbL);
    k_gates<<<dim3((B_ * S_) / BM, NGATE / BN), 256, 0, stream>>>(
        x, WsH, WsL, bi, bo, bg, c_out, h_out);
    k_rec<<<64, 256, 0, stream>>>(c0, c_out, h_out, UsH, UsL, hbH, hbL, flags);
}

// Round 16
// 4812.411 us; speedup vs baseline: 1.7422x; 1.0347x over previous
//
#include <hip/hip_runtime.h>
#include <stdint.h>

#define B_    32
#define S_    1024
#define HIN   1024
#define NBLK  64
#define DBLK  16
#define HOUT  1024
#define NGATE 1152   // 64 i + 64 o + 1024 g
#define NSLICE 32    // gate slices (32 Ug rows + 2 Ui + 2 Uo each)

typedef __attribute__((ext_vector_type(8))) __bf16 bf16x8;
typedef __attribute__((ext_vector_type(4))) float  f32x4;

__device__ __forceinline__ unsigned short f2bf(float f) {
    union { float f; unsigned u; } v; v.f = f;
    return (unsigned short)((v.u + 0x7fffu + ((v.u >> 16) & 1u)) >> 16);
}
__device__ __forceinline__ float bf2f(unsigned short h) {
    union { unsigned u; float f; } v; v.u = ((unsigned)h) << 16; return v.f;
}
// fp32 -> hi+lo bf16 (v ~= hi + lo, residual <= 2^-18 |v|)
__device__ __forceinline__ void split1(float f, unsigned short& hi, unsigned short& lo) {
    hi = f2bf(f);
    lo = f2bf(f - bf2f(hi));
}

// gate-row mapping for a slice: rows 0..31 = Ug[slice*32+r], 32..33 = Ui[2s..], 34..35 = Uo[2s..]
__device__ __forceinline__ int slice_row(int slice, int r) {
    return (r < 32) ? (128 + slice * 32 + r)
         : (r < 34) ? (slice * 2 + (r - 32))
                    : (64 + slice * 2 + (r - 34));
}

// ---------------- phase 0: split W,U into hi/lo bf16; split h0 into planes ----------------
__global__ void k_init(const float* __restrict__ Wi, const float* __restrict__ Wo,
                       const float* __restrict__ Wg,
                       const float* __restrict__ Ui, const float* __restrict__ Uo,
                       const float* __restrict__ Ug, const float* __restrict__ h0,
                       unsigned short* __restrict__ WsH, unsigned short* __restrict__ WsL,
                       unsigned short* __restrict__ UsH, unsigned short* __restrict__ UsL,
                       unsigned short* __restrict__ hbH, unsigned short* __restrict__ hbL)
{
    int idx = blockIdx.x * 256 + threadIdx.x;
    const int nW = NGATE * HOUT / 4;           // 294912 quads per matrix set
    float4 v; unsigned short *dH, *dL;
    if (idx < nW) {
        int f = idx * 4; int row = f >> 10, k = f & 1023;
        const float* src = (row < 64)  ? (Wi + (size_t)row * HIN)
                         : (row < 128) ? (Wo + (size_t)(row - 64) * HIN)
                                       : (Wg + (size_t)(row - 128) * HIN);
        v = *(const float4*)(src + k);
        dH = WsH + f; dL = WsL + f;
    } else if (idx < 2 * nW) {
        int f = (idx - nW) * 4; int row = f >> 10, k = f & 1023;
        const float* src = (row < 64)  ? (Ui + (size_t)row * HOUT)
                         : (row < 128) ? (Uo + (size_t)(row - 64) * HOUT)
                                       : (Ug + (size_t)(row - 128) * HOUT);
        v = *(const float4*)(src + k);
        dH = UsH + f; dL = UsL + f;
    } else {
        int f = (idx - 2 * nW) * 4;
        if (f >= B_ * HOUT) return;
        v = *(const float4*)(h0 + f);
        dH = hbH + f; dL = hbL + f;            // slot 0
    }
    unsigned short th[4], tl[4];
    split1(v.x, th[0], tl[0]); split1(v.y, th[1], tl[1]);
    split1(v.z, th[2], tl[2]); split1(v.w, th[3], tl[3]);
    *(uint2*)dH = *(const uint2*)th;
    *(uint2*)dL = *(const uint2*)tl;
}

// ---------------- phase 1: gate pre-projection GEMM (bf16x3) ----------------
#define BM 128
#define BN 128
#define BK 32
#define LDP 56

__global__ __launch_bounds__(256) void k_gates(
    const float* __restrict__ x,
    const unsigned short* __restrict__ WsH, const unsigned short* __restrict__ WsL,
    const float* __restrict__ bi, const float* __restrict__ bo, const float* __restrict__ bg,
    float* __restrict__ c_out, float* __restrict__ h_out)
{
    __shared__ unsigned short AlH[BM][LDP], AlL[BM][LDP];
    __shared__ unsigned short BlH[BN][LDP], BlL[BN][LDP];
    const int tid  = threadIdx.x;
    const int bm   = blockIdx.x, bn = blockIdx.y;
    const int wave = tid >> 6,  lane = tid & 63;
    const int l15  = lane & 15, l4 = lane >> 4;
    const int wm   = wave >> 1, wn = wave & 1;
    const int rbase = tid >> 3;          // 0..31
    const int c4    = (tid & 7) * 4;     // 0..28

    f32x4 acc[4][4] = {};

    for (int kk = 0; kk < HIN; kk += BK) {
        #pragma unroll
        for (int i = 0; i < 4; ++i) {
            int row = rbase + 32 * i;
            float4 v = *(const float4*)(x + (size_t)(bm * BM + row) * HIN + kk + c4);
            unsigned short th[4], tl[4];
            split1(v.x, th[0], tl[0]); split1(v.y, th[1], tl[1]);
            split1(v.z, th[2], tl[2]); split1(v.w, th[3], tl[3]);
            *(uint2*)&AlH[row][c4] = *(const uint2*)th;
            *(uint2*)&AlL[row][c4] = *(const uint2*)tl;
            int n = bn * BN + row;
            *(uint2*)&BlH[row][c4] = *(const uint2*)(WsH + (size_t)n * HIN + kk + c4);
            *(uint2*)&BlL[row][c4] = *(const uint2*)(WsL + (size_t)n * HIN + kk + c4);
        }
        __syncthreads();
        uint4 ah[4], al[4], bh4[4], bl4[4];
        #pragma unroll
        for (int mi = 0; mi < 4; ++mi) {
            ah[mi] = *(const uint4*)&AlH[wm * 64 + mi * 16 + l15][l4 * 8];
            al[mi] = *(const uint4*)&AlL[wm * 64 + mi * 16 + l15][l4 * 8];
        }
        #pragma unroll
        for (int ni = 0; ni < 4; ++ni) {
            bh4[ni] = *(const uint4*)&BlH[wn * 64 + ni * 16 + l15][l4 * 8];
            bl4[ni] = *(const uint4*)&BlL[wn * 64 + ni * 16 + l15][l4 * 8];
        }
        #pragma unroll
        for (int mi = 0; mi < 4; ++mi) {
            #pragma unroll
            for (int ni = 0; ni < 4; ++ni) {
                acc[mi][ni] = __builtin_amdgcn_mfma_f32_16x16x32_bf16(
                    __builtin_bit_cast(bf16x8, ah[mi]), __builtin_bit_cast(bf16x8, bh4[ni]),
                    acc[mi][ni], 0, 0, 0);
                acc[mi][ni] = __builtin_amdgcn_mfma_f32_16x16x32_bf16(
                    __builtin_bit_cast(bf16x8, ah[mi]), __builtin_bit_cast(bf16x8, bl4[ni]),
                    acc[mi][ni], 0, 0, 0);
                acc[mi][ni] = __builtin_amdgcn_mfma_f32_16x16x32_bf16(
                    __builtin_bit_cast(bf16x8, al[mi]), __builtin_bit_cast(bf16x8, bh4[ni]),
                    acc[mi][ni], 0, 0, 0);
            }
        }
        __syncthreads();
    }

    #pragma unroll
    for (int ni = 0; ni < 4; ++ni) {
        int n = bn * BN + wn * 64 + ni * 16 + l15;
        float bv = (n < 64) ? bi[n] : (n < 128) ? bo[n - 64] : bg[n - 128];
        #pragma unroll
        for (int mi = 0; mi < 4; ++mi) {
            #pragma unroll
            for (int r = 0; r < 4; ++r) {
                int m = bm * BM + wm * 64 + mi * 16 + l4 * 4 + r;
                float val = acc[mi][ni][r] + bv;
                if (n >= 128) {
                    h_out[(size_t)m * HOUT + (n - 128)] = val;
                } else if (n < 64) {
                    c_out[((size_t)m * NBLK + n) * DBLK + 0] = val;
                } else {
                    c_out[((size_t)m * NBLK + (n - 64)) * DBLK + 1] = val;
                }
            }
        }
    }
}

// ---------------- phase 2: persistent lockstep recurrence (bf16x3) ----------------
// 64 WGs x 256 thr. slice = bid&31, group = bid>>5 (batches [16g,+16)).
// R16 = R15 compute body + publish-leg surgery:
//  * per-wave QUARTER-FLAGS: vmcnt is per-wave, so each wave drains its own 2
//    agent publishes then stores flags[g][slice][wave] -- NO [B] barrier.
//    Consumer polls 128 quarter-flags as 64 x 8B atomic loads.
//  * outputs (c_out/h_out, partial-line -> RFO ~900cy) moved AFTER the flag:
//    their latency overlaps the next poll instead of sitting pre-flag.
//  * prefetch moved AFTER the staging asm: stage drain excludes cold-HBM loads.
__global__ __launch_bounds__(256, 1) void k_rec(
    const float* __restrict__ c0,
    float* __restrict__ c_out, float* __restrict__ h_out,
    const unsigned short* __restrict__ UsH, const unsigned short* __restrict__ UsL,
    unsigned short* __restrict__ hbH, unsigned short* __restrict__ hbL,
    unsigned int* __restrict__ flags)
{
    __shared__ unsigned short Wlo[37][1032];   // 74.6 KB (row 36 = zeros)
    __shared__ unsigned short HaH[16][1032];   // 33 KB
    __shared__ unsigned short HaL[16][1032];   // 33 KB
    __shared__ float preW[4][16][53];          // 13.6 KB per-wave partials (pad 53)

    const int tid   = threadIdx.x;
    const int slice = blockIdx.x & 31;
    const int group = blockIdx.x >> 5;     // 0 or 1
    const int wave  = tid >> 6, lane = tid & 63;
    const int l15   = lane & 15, l4 = lane >> 4;

    // fill Wlo (lo-plane weights) into LDS; row 36 zeroed
    for (int idx = tid; idx < 37 * 128; idx += 256) {
        int row = idx >> 7, c8 = idx & 127;
        uint4 v = make_uint4(0, 0, 0, 0);
        if (row < 36)
            v = *(const uint4*)(UsL + (size_t)slice_row(slice, row) * HOUT + c8 * 8);
        *(uint4*)&Wlo[row][c8 * 8] = v;
    }

    // hi-plane B-fragments for this wave's K-quarter (L2-streamed by compiler; OK)
    int wrow[3];
    uint4 bwh[3][8];
    #pragma unroll
    for (int nt = 0; nt < 3; ++nt) {
        int grow = nt * 16 + l15;
        bool valid = grow < 36;
        wrow[nt] = valid ? grow : 36;
        int srow = valid ? slice_row(slice, grow) : 0;
        const unsigned short* ph = UsH + (size_t)srow * HOUT + wave * 256 + l4 * 8;
        #pragma unroll
        for (int ks = 0; ks < 8; ++ks)
            bwh[nt][ks] = valid ? *(const uint4*)(ph + ks * 32) : make_uint4(0, 0, 0, 0);
    }

    // per-thread epilogue mapping: 2 consecutive h-cols
    const int e0   = tid * 2;
    const int bl   = e0 >> 5;             // 0..15 batch-in-group
    const int col0 = e0 & 31;             // even
    const int Bg   = group * 16 + bl;
    const int hcol = slice * 32 + col0;
    const int blkI = hcol >> 4, d0 = hcol & 15;
    float cr0 = c0[((size_t)Bg * NBLK + blkI) * DBLK + d0];
    float cr1 = c0[((size_t)Bg * NBLK + blkI) * DBLK + d0 + 1];

    unsigned int* flagbase = flags + (size_t)group * NSLICE * 32;
    unsigned int* myflag   = flagbase + slice * 32 + wave;            // quarter-flag dword
    // poll coverage: lane l watches slice (l&31), quarter-pair (l>>5) as one 8B load
    unsigned long long* pollp =
        (unsigned long long*)(flagbase + (lane & 31) * 32 + 2 * (lane >> 5));

    // step-0 gate preactivation prefetch
    float xg0, xg1, xi, xo;
    {
        size_t r0 = (size_t)Bg * S_;
        xg0 = h_out[r0 * HOUT + hcol];
        xg1 = h_out[r0 * HOUT + hcol + 1];
        xi  = c_out[(r0 * NBLK + blkI) * DBLK + 0];
        xo  = c_out[(r0 * NBLK + blkI) * DBLK + 1];
    }

    __syncthreads();   // Wlo ready

    for (int t = 0; t < S_; ++t) {
        // ---- 1. poll (wave 0 only; 64 lanes x 8B cover all 128 quarter-flags)
        if (t > 0) {
            if (wave == 0) {
                unsigned long long v;
                do {
                    v = __hip_atomic_load(pollp, __ATOMIC_RELAXED, __HIP_MEMORY_SCOPE_AGENT);
                } while (!__all((int)((unsigned)v >= (unsigned)t &&
                                      (unsigned)(v >> 32) >= (unsigned)t)));
            }
            __syncthreads();
        }

        // ---- 2. bulk-stage h_t hi/lo planes (R11 asm verbatim): 32 coherent loads
        //         in flight, ONE drain. thread tid covers col-chunk tid*8B of all
        //         16 rows -> wave w stages exactly its K-quarter.
        {
            const char* bH = (const char*)(hbH + ((size_t)(t & 1) * B_ + group * 16) * HOUT) + tid * 8;
            const char* bL = (const char*)(hbL + ((size_t)(t & 1) * B_ + group * 16) * HOUT) + tid * 8;
            unsigned long long vh[16], vl[16];
            asm volatile(
                "global_load_dwordx2 %0, %32, off sc0 sc1\n\t"
                "global_load_dwordx2 %1, %32, off offset:2048 sc0 sc1\n\t"
                "global_load_dwordx2 %2, %33, off sc0 sc1\n\t"
                "global_load_dwordx2 %3, %33, off offset:2048 sc0 sc1\n\t"
                "global_load_dwordx2 %4, %34, off sc0 sc1\n\t"
                "global_load_dwordx2 %5, %34, off offset:2048 sc0 sc1\n\t"
                "global_load_dwordx2 %6, %35, off sc0 sc1\n\t"
                "global_load_dwordx2 %7, %35, off offset:2048 sc0 sc1\n\t"
                "global_load_dwordx2 %8, %36, off sc0 sc1\n\t"
                "global_load_dwordx2 %9, %36, off offset:2048 sc0 sc1\n\t"
                "global_load_dwordx2 %10, %37, off sc0 sc1\n\t"
                "global_load_dwordx2 %11, %37, off offset:2048 sc0 sc1\n\t"
                "global_load_dwordx2 %12, %38, off sc0 sc1\n\t"
                "global_load_dwordx2 %13, %38, off offset:2048 sc0 sc1\n\t"
                "global_load_dwordx2 %14, %39, off sc0 sc1\n\t"
                "global_load_dwordx2 %15, %39, off offset:2048 sc0 sc1\n\t"
                "global_load_dwordx2 %16, %40, off sc0 sc1\n\t"
                "global_load_dwordx2 %17, %40, off offset:2048 sc0 sc1\n\t"
                "global_load_dwordx2 %18, %41, off sc0 sc1\n\t"
                "global_load_dwordx2 %19, %41, off offset:2048 sc0 sc1\n\t"
                "global_load_dwordx2 %20, %42, off sc0 sc1\n\t"
                "global_load_dwordx2 %21, %42, off offset:2048 sc0 sc1\n\t"
                "global_load_dwordx2 %22, %43, off sc0 sc1\n\t"
                "global_load_dwordx2 %23, %43, off offset:2048 sc0 sc1\n\t"
                "global_load_dwordx2 %24, %44, off sc0 sc1\n\t"
                "global_load_dwordx2 %25, %44, off offset:2048 sc0 sc1\n\t"
                "global_load_dwordx2 %26, %45, off sc0 sc1\n\t"
                "global_load_dwordx2 %27, %45, off offset:2048 sc0 sc1\n\t"
                "global_load_dwordx2 %28, %46, off sc0 sc1\n\t"
                "global_load_dwordx2 %29, %46, off offset:2048 sc0 sc1\n\t"
                "global_load_dwordx2 %30, %47, off sc0 sc1\n\t"
                "global_load_dwordx2 %31, %47, off offset:2048 sc0 sc1\n\t"
                "s_waitcnt vmcnt(0)\n\t"
                : "=&v"(vh[0]), "=&v"(vh[1]), "=&v"(vh[2]), "=&v"(vh[3]),
                  "=&v"(vh[4]), "=&v"(vh[5]), "=&v"(vh[6]), "=&v"(vh[7]),
                  "=&v"(vh[8]), "=&v"(vh[9]), "=&v"(vh[10]), "=&v"(vh[11]),
                  "=&v"(vh[12]), "=&v"(vh[13]), "=&v"(vh[14]), "=&v"(vh[15]),
                  "=&v"(vl[0]), "=&v"(vl[1]), "=&v"(vl[2]), "=&v"(vl[3]),
                  "=&v"(vl[4]), "=&v"(vl[5]), "=&v"(vl[6]), "=&v"(vl[7]),
                  "=&v"(vl[8]), "=&v"(vl[9]), "=&v"(vl[10]), "=&v"(vl[11]),
                  "=&v"(vl[12]), "=&v"(vl[13]), "=&v"(vl[14]), "=&v"(vl[15])
                : "v"(bH), "v"(bH + 4096), "v"(bH + 8192), "v"(bH + 12288),
                  "v"(bH + 16384), "v"(bH + 20480), "v"(bH + 24576), "v"(bH + 28672),
                  "v"(bL), "v"(bL + 4096), "v"(bL + 8192), "v"(bL + 12288),
                  "v"(bL + 16384), "v"(bL + 20480), "v"(bL + 24576), "v"(bL + 28672)
                : "memory");
            #pragma unroll
            for (int it = 0; it < 16; ++it) {
                *(unsigned long long*)&HaH[it][tid * 4] = vh[it];
                *(unsigned long long*)&HaL[it][tid * 4] = vl[it];
            }
        }
        // NO barrier: this wave reads only its own staged K-quarter.

        // ---- 3. next-step prefetch AFTER the stage drain: its cold-HBM latency
        //         retires during the MFMA phase (pinned between the two asm fences)
        float nxg0 = 0.f, nxg1 = 0.f, nxi = 0.f, nxo = 0.f;
        if (t + 1 < S_) {
            size_t rn = (size_t)Bg * S_ + (t + 1);
            nxg0 = h_out[rn * HOUT + hcol];
            nxg1 = h_out[rn * HOUT + hcol + 1];
            nxi  = c_out[(rn * NBLK + blkI) * DBLK + 0];
            nxo  = c_out[(rn * NBLK + blkI) * DBLK + 1];
        }

        // ---- 4. K-split MFMA: all 36 gate rows over MY quarter (A from LDS)
        f32x4 acc[3] = {};
        #pragma unroll
        for (int ks = 0; ks < 8; ++ks) {
            uint4 auh = *(const uint4*)&HaH[l15][wave * 256 + ks * 32 + l4 * 8];
            uint4 aul = *(const uint4*)&HaL[l15][wave * 256 + ks * 32 + l4 * 8];
            #pragma unroll
            for (int nt = 0; nt < 3; ++nt) {
                uint4 bl_ = *(const uint4*)&Wlo[wrow[nt]][wave * 256 + ks * 32 + l4 * 8];
                acc[nt] = __builtin_amdgcn_mfma_f32_16x16x32_bf16(
                        __builtin_bit_cast(bf16x8, auh), __builtin_bit_cast(bf16x8, bwh[nt][ks]), acc[nt], 0, 0, 0);
                acc[nt] = __builtin_amdgcn_mfma_f32_16x16x32_bf16(
                        __builtin_bit_cast(bf16x8, aul), __builtin_bit_cast(bf16x8, bwh[nt][ks]), acc[nt], 0, 0, 0);
                acc[nt] = __builtin_amdgcn_mfma_f32_16x16x32_bf16(
                        __builtin_bit_cast(bf16x8, auh), __builtin_bit_cast(bf16x8, bl_), acc[nt], 0, 0, 0);
            }
        }

        // ---- 5. per-wave partials to LDS (plain writes; every cell written)
        #pragma unroll
        for (int nt = 0; nt < 3; ++nt) {
            #pragma unroll
            for (int r = 0; r < 4; ++r)
                preW[wave][l4 * 4 + r][nt * 16 + l15] = acc[nt][r];
        }
        __syncthreads();   // [A] all quarters in LDS

        // ---- 6. epilogue: sum 4 wave-partials + prefetched xg/xi/xo
        float gp0 = xg0, gp1 = xg1, ip = xi, op = xo;
        #pragma unroll
        for (int w = 0; w < 4; ++w) {
            gp0 += preW[w][bl][col0];
            gp1 += preW[w][bl][col0 + 1];
            ip  += preW[w][bl][32 + (col0 >> 4)];
            op  += preW[w][bl][34 + (col0 >> 4)];
        }
        float ig  = 1.f / (1.f + __expf(-ip));
        float og  = 1.f / (1.f + __expf(-op));
        cr0 += ig * tanhf(gp0);
        cr1 += ig * tanhf(gp1);
        float h0v = og * tanhf(cr0);
        float h1v = og * tanhf(cr1);

        // ---- 7. publish h_{t+1} (agent scope) -> per-wave drain -> quarter-flag
        unsigned short h0h, h0l, h1h, h1l;
        split1(h0v, h0h, h0l); split1(h1v, h1h, h1l);
        size_t dsto = ((size_t)((t + 1) & 1) * B_ + Bg) * HOUT + hcol;
        __hip_atomic_store((unsigned int*)(hbH + dsto),
                           (unsigned)h0h | ((unsigned)h1h << 16),
                           __ATOMIC_RELAXED, __HIP_MEMORY_SCOPE_AGENT);
        __hip_atomic_store((unsigned int*)(hbL + dsto),
                           (unsigned)h0l | ((unsigned)h1l << 16),
                           __ATOMIC_RELAXED, __HIP_MEMORY_SCOPE_AGENT);

        asm volatile("s_waitcnt vmcnt(0)" ::: "memory");   // per-wave: own publishes only
        if (lane == 0)
            __hip_atomic_store(myflag, (unsigned)(t + 1),
                               __ATOMIC_RELAXED, __HIP_MEMORY_SCOPE_AGENT);

        // ---- 8. outputs AFTER the flag (RFO latency overlaps next poll)
        size_t ro = (size_t)Bg * S_ + t;
        c_out[(ro * NBLK + blkI) * DBLK + d0]     = cr0;
        c_out[(ro * NBLK + blkI) * DBLK + d0 + 1] = cr1;
        h_out[ro * HOUT + hcol]     = h0v;
        h_out[ro * HOUT + hcol + 1] = h1v;

        // ---- 9. rotate prefetched gate preactivations
        xg0 = nxg0; xg1 = nxg1; xi = nxi; xo = nxo;
    }
}

// ---------------- launch ----------------
extern "C" void kernel_launch(void* const* d_in, const int* in_sizes, int n_in,
                              void* d_out, int out_size, void* d_ws, size_t ws_size,
                              hipStream_t stream) {
    const float* x  = (const float*)d_in[0];
    const float* h0 = (const float*)d_in[1];
    const float* c0 = (const float*)d_in[2];
    const float* Wi = (const float*)d_in[3];
    const float* bi = (const float*)d_in[4];
    const float* Wo = (const float*)d_in[5];
    const float* bo = (const float*)d_in[6];
    const float* Wg = (const float*)d_in[7];
    const float* bg = (const float*)d_in[8];
    const float* Ui = (const float*)d_in[9];
    const float* Uo = (const float*)d_in[10];
    const float* Ug = (const float*)d_in[11];

    float* c_out = (float*)d_out;
    float* h_out = c_out + (size_t)B_ * S_ * NBLK * DBLK;

    unsigned short* WsH  = (unsigned short*)d_ws;                    // [1152][1024]
    unsigned short* WsL  = WsH + (size_t)NGATE * HOUT;
    unsigned short* UsH  = WsL + (size_t)NGATE * HOUT;
    unsigned short* UsL  = UsH + (size_t)NGATE * HOUT;
    unsigned short* hbH  = UsL + (size_t)NGATE * HOUT;               // [2][32][1024]
    unsigned short* hbL  = hbH + (size_t)2 * B_ * HOUT;
    unsigned int*   flags = (unsigned int*)(hbL + (size_t)2 * B_ * HOUT); // [2][32]x128B

    hipMemsetAsync(flags, 0, 64 * 32 * sizeof(unsigned int), stream);
    k_init<<<2336, 256, 0, stream>>>(Wi, Wo, Wg, Ui, Uo, Ug, h0, WsH, WsL, UsH, UsL, hbH, hbL);
    k_gates<<<dim3((B_ * S_) / BM, NGATE / BN), 256, 0, stream>>>(
        x, WsH, WsL, bi, bo, bg, c_out, h_out);
    k_rec<<<64, 256, 0, stream>>>(c0, c_out, h_out, UsH, UsL, hbH, hbL, flags);
}